// Round 2
// baseline (493.093 us; speedup 1.0000x reference)
//
#include <hip/hip_runtime.h>

typedef short bf16x8 __attribute__((ext_vector_type(8)));
typedef float f32x4 __attribute__((ext_vector_type(4)));
typedef unsigned short u16;

__device__ __forceinline__ u16 f2bf(float f) {
    unsigned u = __builtin_bit_cast(unsigned, f);
    return (u16)((u + 0x7fffu + ((u >> 16) & 1u)) >> 16);   // RNE
}

// ---------------- kernel 1: pad + convert x to bf16 --------------------------
// xpad[b][r][d], r in [0,8192): rows < 4096 are zeros (causal mask), 4096+t = x[b,t,:]
__global__ void k_pad_x(const float* __restrict__ x, u16* __restrict__ xpad) {
    int gid = blockIdx.x * 256 + threadIdx.x;        // handles 4 elems
    int b   = gid >> 17;
    int rem = gid & 131071;
    int r   = rem >> 4;
    int c4  = rem & 15;
    u16 o0 = 0, o1 = 0, o2 = 0, o3 = 0;
    if (r >= 4096) {
        const f32x4 v = *(const f32x4*)(x + ((b << 12) + (r - 4096)) * 64 + c4 * 4);
        o0 = f2bf(v.x); o1 = f2bf(v.y); o2 = f2bf(v.z); o3 = f2bf(v.w);
    }
    u16* p = xpad + ((b << 13) + r) * 64 + c4 * 4;
    p[0] = o0; p[1] = o1; p[2] = o2; p[3] = o3;
}

// ---------------- kernel 1b: transpose Mp+-Mm into [k][o][d] fp32 ------------
__global__ void k_prep(const float* __restrict__ Mp, const float* __restrict__ Mm,
                       float* __restrict__ ApT, float* __restrict__ AmT) {
    __shared__ float tp[64 * 65], tm[64 * 65];
    const int k = blockIdx.x, tid = threadIdx.x;
    for (int f = tid; f < 4096; f += 256) {          // f = d*64 + o
        int d = f >> 6, o = f & 63;
        float p = Mp[k * 4096 + f], m = Mm[k * 4096 + f];
        tp[o * 65 + d] = p + m;
        tm[o * 65 + d] = p - m;
    }
    __syncthreads();
    for (int f = tid; f < 4096; f += 256) {          // f = o*64 + d
        int o = f >> 6, d = f & 63;
        ApT[k * 4096 + f] = tp[o * 65 + d];
        AmT[k * 4096 + f] = tm[o * 65 + d];
    }
}

// ---------------- kernel 2: build Wtot[s][o][d] (bf16) -----------------------
// W[s][o][d] = sum_k phi[s,k]*(Mp + sgn(s)*Mm)[k,d,o]  (+ M[o,d,s] for s<3)
// Coalesced A loads (registers), wave-uniform phi (scalar loads), no LDS.
__global__ __launch_bounds__(256)
void k_build_w(const float* __restrict__ phi, const float* __restrict__ ApT,
               const float* __restrict__ AmT, const float* __restrict__ Mar,
               u16* __restrict__ wg) {
    const int sb = blockIdx.x;                 // 0..63  -> 64 s-values
    const int qb = blockIdx.y;                 // 0..15  -> 256 q = o*64+d
    const int s0 = sb * 64;
    const int q  = qb * 256 + threadIdx.x;
    const int o  = q >> 6, d = q & 63;

    float ap[40], am[40];
    #pragma unroll
    for (int k = 0; k < 40; ++k) { ap[k] = ApT[k * 4096 + q]; am[k] = AmT[k * 4096 + q]; }

    for (int j = 0; j < 64; j += 2) {
        const float* ph = phi + (s0 + j) * 40;       // wave-uniform -> s_load
        float a0 = 0.f, a1 = 0.f, b0 = 0.f, b1 = 0.f;
        #pragma unroll
        for (int k = 0; k < 40; k += 2) { a0 += ph[k] * ap[k]; a1 += ph[k + 1] * ap[k + 1]; }
        #pragma unroll
        for (int k = 0; k < 40; k += 2) { b0 += ph[40 + k] * am[k]; b1 += ph[41 + k] * am[k + 1]; }
        float ev = a0 + a1, ov = b0 + b1;
        int s = s0 + j;
        if (s < 3)     ev += Mar[o * 192 + d * 3 + s];       // fold AR (s = 0, 2)
        if (s + 1 < 3) ov += Mar[o * 192 + d * 3 + s + 1];   // fold AR (s = 1)
        wg[(size_t)s * 4096 + q]       = f2bf(ev);
        wg[(size_t)(s + 1) * 4096 + q] = f2bf(ov);
    }
}

// ---------------- kernel 3: triangular conv-GEMM via MFMA --------------------
// Persistent blocks, dynamic task counter. Task T -> (I, Jg): I(I+1)/2 <= T.
// t-rows [128I,128I+128) x 2 batches (M=256), s in [128Jg, 128Jg+128) (K=128*64).
// x window (255 rows/batch) staged once in LDS; W B-frags stream from global
// (register double-buffer) -> ZERO barriers in the 128-iteration K-loop.
__global__ __launch_bounds__(256, 2)
void k_spectral(const u16* __restrict__ xpad, const u16* __restrict__ wg,
                float* __restrict__ out, int* __restrict__ counter) {
    __shared__ __align__(16) u16 xs[2 * 255 * 64];   // 63.75 KB swizzled window
    __shared__ int sh;

    const int tid  = threadIdx.x;
    const int lane = tid & 63, w = tid >> 6;
    const int m15  = lane & 15, q4 = lane >> 4;
    const int batch = w >> 1, tb_loc = (w & 1) << 6;

    for (;;) {
        __syncthreads();                             // xs/sh reuse guard
        if (tid == 0) sh = atomicAdd(counter, 1);
        __syncthreads();
        const int T = sh;
        if (T >= 528) break;

        // T -> (I, Jg) with tri(I) <= T < tri(I+1)
        int I = (int)((sqrtf(8.f * (float)T + 1.f) - 1.f) * 0.5f);
        while ((I + 1) * (I + 2) / 2 <= T) ++I;
        while (I * (I + 1) / 2 > T) --I;
        const int Jg = T - I * (I + 1) / 2;
        const int t0 = I << 7, s0g = Jg << 7;
        const int base = 4096 + t0 - s0g - 127;      // in [3969, 7937]

        // ---- stage x window: rows r in [0,255), g = base+r <= 8191 ----
        #pragma unroll
        for (int b = 0; b < 2; ++b) {
            for (int f = tid; f < 2040; f += 256) {  // 255 rows x 8 chunks
                int r = f >> 3, c = f & 7;
                bf16x8 v = *(const bf16x8*)(xpad + ((b << 13) + base + r) * 64 + c * 8);
                *(bf16x8*)(xs + ((b * 255 + r) * 8 + (c ^ (r & 7))) * 8) = v;
            }
        }
        __syncthreads();

        f32x4 acc[4][4];
        #pragma unroll
        for (int mt = 0; mt < 4; ++mt)
            #pragma unroll
            for (int nt = 0; nt < 4; ++nt)
                acc[mt][nt] = (f32x4){0.f, 0.f, 0.f, 0.f};

        const u16* wb = wg + (size_t)s0g * 4096 + m15 * 64 + q4 * 8;
        const u16* xbase = xs + batch * (255 * 64);

        // prefetch B-frags for first s
        bf16x8 bcur[4][2], bnxt[4][2];
        #pragma unroll
        for (int nt = 0; nt < 4; ++nt)
            #pragma unroll
            for (int ks = 0; ks < 2; ++ks)
                bcur[nt][ks] = *(const bf16x8*)(wb + nt * 1024 + ks * 32);

        #pragma unroll 2
        for (int ds = 0; ds < 128; ++ds) {
            // prefetch next s (last iter overreads into ApT region -- unused, in-bounds of ws)
            const u16* wn = wb + (size_t)(ds + 1) * 4096;
            #pragma unroll
            for (int nt = 0; nt < 4; ++nt)
                #pragma unroll
                for (int ks = 0; ks < 2; ++ks)
                    bnxt[nt][ks] = *(const bf16x8*)(wn + nt * 1024 + ks * 32);

            const int rb = tb_loc + m15 + 127 - ds;
            bf16x8 af[4][2];
            #pragma unroll
            for (int mt = 0; mt < 4; ++mt) {
                int r = rb + mt * 16;
                #pragma unroll
                for (int ks = 0; ks < 2; ++ks) {
                    int c = (ks * 4 + q4) ^ (r & 7);
                    af[mt][ks] = *(const bf16x8*)(xbase + (r * 8 + c) * 8);
                }
            }
            #pragma unroll
            for (int mt = 0; mt < 4; ++mt)
                #pragma unroll
                for (int nt = 0; nt < 4; ++nt) {
                    acc[mt][nt] = __builtin_amdgcn_mfma_f32_16x16x32_bf16(
                        af[mt][0], bcur[nt][0], acc[mt][nt], 0, 0, 0);
                    acc[mt][nt] = __builtin_amdgcn_mfma_f32_16x16x32_bf16(
                        af[mt][1], bcur[nt][1], acc[mt][nt], 0, 0, 0);
                }
            #pragma unroll
            for (int nt = 0; nt < 4; ++nt) {
                bcur[nt][0] = bnxt[nt][0];
                bcur[nt][1] = bnxt[nt][1];
            }
        }

        // ---- epilogue: fp32 atomic accumulation (once per 128 s) ----
        const int tb = t0 + tb_loc;
        #pragma unroll
        for (int mt = 0; mt < 4; ++mt) {
            int t = tb + mt * 16 + q4 * 4;
            #pragma unroll
            for (int nt = 0; nt < 4; ++nt) {
                int o = nt * 16 + m15;
                float* op = out + ((batch << 12) + t) * 64 + o;
                #pragma unroll
                for (int r = 0; r < 4; ++r)
                    atomicAdd(op + r * 64, acc[mt][nt][r]);
            }
        }
    }
}

// ---------------------------------------------------------------------------
extern "C" void kernel_launch(void* const* d_in, const int* in_sizes, int n_in,
                              void* d_out, int out_size, void* d_ws, size_t ws_size,
                              hipStream_t stream) {
    const float* x   = (const float*)d_in[0];   // (2, 4096, 64)
    const float* phi = (const float*)d_in[1];   // (4096, 40)
    const float* M   = (const float*)d_in[2];   // (64, 64, 3)
    const float* Mp  = (const float*)d_in[3];   // (40, 64, 64)
    const float* Mm  = (const float*)d_in[4];   // (40, 64, 64)
    float* out = (float*)d_out;                 // (2, 4096, 64)

    // ws layout: [0,4) task counter | 4096: xpad 2 MiB | wg 32 MiB | ApT/AmT 1.3 MiB
    int* counter = (int*)d_ws;
    u16* xpad = (u16*)((char*)d_ws + 4096);
    u16* wg   = (u16*)((char*)d_ws + 4096 + 2097152);
    float* ApT = (float*)((char*)d_ws + 4096 + 2097152 + 33554432);
    float* AmT = ApT + 40 * 4096;

    hipMemsetAsync(d_ws, 0, 4, stream);
    hipMemsetAsync(d_out, 0, 2 * 4096 * 64 * sizeof(float), stream);
    k_pad_x<<<1024, 256, 0, stream>>>(x, xpad);
    k_prep<<<40, 256, 0, stream>>>(Mp, Mm, ApT, AmT);
    k_build_w<<<dim3(64, 16), 256, 0, stream>>>(phi, ApT, AmT, M, wg);
    k_spectral<<<512, 256, 0, stream>>>(xpad, wg, out, counter);
}

// Round 3
// 267.885 us; speedup vs baseline: 1.8407x; 1.8407x over previous
//
#include <hip/hip_runtime.h>

typedef short bf16x8 __attribute__((ext_vector_type(8)));
typedef float f32x4 __attribute__((ext_vector_type(4)));
typedef float f32x16 __attribute__((ext_vector_type(16)));
typedef unsigned short u16;

__device__ __forceinline__ u16 f2bf(float f) {
    unsigned u = __builtin_bit_cast(unsigned, f);
    return (u16)((u + 0x7fffu + ((u >> 16) & 1u)) >> 16);   // RNE
}

// ---------------- kernel 1 (fused): pad x -> bf16  AND  transpose Mp/Mm ------
// blocks [0,1024): xpad[b][r][d] (r<4096 zeros, 4096+t = x[b,t,:])
// blocks [1024,1064): ApT/AmT[k][o][d] = (Mp +/- Mm)[k][d][o]
__global__ void k_prep(const float* __restrict__ x, u16* __restrict__ xpad,
                       const float* __restrict__ Mp, const float* __restrict__ Mm,
                       float* __restrict__ ApT, float* __restrict__ AmT) {
    __shared__ float tp[64 * 65], tm[64 * 65];
    if (blockIdx.x < 1024) {
        int gid = blockIdx.x * 256 + threadIdx.x;
        int b   = gid >> 17;
        int rem = gid & 131071;
        int r   = rem >> 4;
        int c4  = rem & 15;
        u16 o0 = 0, o1 = 0, o2 = 0, o3 = 0;
        if (r >= 4096) {
            const f32x4 v = *(const f32x4*)(x + ((b << 12) + (r - 4096)) * 64 + c4 * 4);
            o0 = f2bf(v.x); o1 = f2bf(v.y); o2 = f2bf(v.z); o3 = f2bf(v.w);
        }
        u16* p = xpad + ((b << 13) + r) * 64 + c4 * 4;
        p[0] = o0; p[1] = o1; p[2] = o2; p[3] = o3;
    } else {
        const int k = blockIdx.x - 1024, tid = threadIdx.x;
        for (int f = tid; f < 4096; f += 256) {          // f = d*64 + o
            int d = f >> 6, o = f & 63;
            float p = Mp[k * 4096 + f], m = Mm[k * 4096 + f];
            tp[o * 65 + d] = p + m;
            tm[o * 65 + d] = p - m;
        }
        __syncthreads();
        for (int f = tid; f < 4096; f += 256) {          // f = o*64 + d
            int o = f >> 6, d = f & 63;
            ApT[k * 4096 + f] = tp[o * 65 + d];
            AmT[k * 4096 + f] = tm[o * 65 + d];
        }
    }
}

// ---------------- kernel 2: build Wtot[s][o][d] (bf16) -----------------------
// W[s][o][d] = sum_k phi[s,k]*(Mp + sgn(s)*Mm)[k,d,o]  (+ M[o,d,s] for s<3)
__global__ __launch_bounds__(256)
void k_build_w(const float* __restrict__ phi, const float* __restrict__ ApT,
               const float* __restrict__ AmT, const float* __restrict__ Mar,
               u16* __restrict__ wg) {
    const int sb = blockIdx.x;                 // 0..63  -> 64 s-values
    const int qb = blockIdx.y;                 // 0..15  -> 256 q = o*64+d
    const int s0 = sb * 64;
    const int q  = qb * 256 + threadIdx.x;
    const int o  = q >> 6, d = q & 63;

    float ap[40], am[40];
    #pragma unroll
    for (int k = 0; k < 40; ++k) { ap[k] = ApT[k * 4096 + q]; am[k] = AmT[k * 4096 + q]; }

    for (int j = 0; j < 64; j += 2) {
        const float* ph = phi + (s0 + j) * 40;           // wave-uniform -> s_load
        float a0 = 0.f, a1 = 0.f, b0 = 0.f, b1 = 0.f;
        #pragma unroll
        for (int k = 0; k < 40; k += 2) { a0 += ph[k] * ap[k]; a1 += ph[k + 1] * ap[k + 1]; }
        #pragma unroll
        for (int k = 0; k < 40; k += 2) { b0 += ph[40 + k] * am[k]; b1 += ph[41 + k] * am[k + 1]; }
        float ev = a0 + a1, ov = b0 + b1;
        int s = s0 + j;
        if (s < 3)     ev += Mar[o * 192 + d * 3 + s];
        if (s + 1 < 3) ov += Mar[o * 192 + d * 3 + s + 1];
        wg[(size_t)s * 4096 + q]       = f2bf(ev);
        wg[(size_t)(s + 1) * 4096 + q] = f2bf(ov);
    }
}

// ---------------- kernel 3: triangular conv-GEMM, 32x32x16 MFMA --------------
// Persistent 512 blocks, dynamic unit counter. Unit U -> (I, J): I(I+1) <= U.
// t-rows [128I, 128I+128) x 2 batches (M=256), s in [64J, 64J+64).
// x window in LDS (48 KB, xor-swizzled), W double-buffered (16 KB), 1 barrier/s.
__global__ __launch_bounds__(256, 2)
void k_spectral(const u16* __restrict__ xpad, const u16* __restrict__ wg,
                float* __restrict__ out, int* __restrict__ counter) {
    __shared__ __align__(16) u16 xs[2 * 192 * 64];       // 48 KB
    __shared__ __align__(16) u16 wsm[2 * 64 * 64];       // 16 KB
    __shared__ int sh;

    const int tid  = threadIdx.x;
    const int lane = tid & 63, w = tid >> 6;
    const int m31  = lane & 31, g2 = lane >> 5;
    const int batch = w >> 1, tb_loc = (w & 1) << 6;     // wave: 64 t-rows of one batch
    const int fo0 = (tid * 2) >> 3, fc0 = (tid * 2) & 7; // W staging chunks
    const int fo1 = (tid * 2 + 1) >> 3, fc1 = (tid * 2 + 1) & 7;

    for (;;) {
        __syncthreads();                                 // xs/wsm/sh reuse guard
        if (tid == 0) sh = atomicAdd(counter, 1);
        __syncthreads();
        const int U = sh;
        if (U >= 1056) break;

        // U -> (I, J): I(I+1) <= U < (I+1)(I+2), J = U - I(I+1) in [0, 2I+2)
        int I = (int)((sqrtf(4.f * (float)U + 1.f) - 1.f) * 0.5f);
        while ((I + 1) * (I + 2) <= U) ++I;
        while (I * (I + 1) > U) --I;
        const int J = U - I * (I + 1);
        const int t0 = I << 7, s0 = J << 6;
        const int base = 4096 + t0 - s0 - 63;            // in [3969, 8001]

        // ---- stage x window: 192 rows/batch, row 191 never read (clamped) ----
        #pragma unroll
        for (int b = 0; b < 2; ++b) {
            #pragma unroll
            for (int ii = 0; ii < 6; ++ii) {
                int f = tid + ii * 256;                  // 0..1535
                int r = f >> 3, c = f & 7;
                int g = base + r;
                if (g > 8191) g = 8191;
                bf16x8 v = *(const bf16x8*)(xpad + ((b << 13) + g) * 64 + c * 8);
                *(bf16x8*)(xs + ((b * 192 + r) * 8 + (c ^ (r & 7))) * 8) = v;
            }
        }
        // prefetch W[s0] (32 B/thread)
        bf16x8 pre0 = *(const bf16x8*)(wg + (size_t)s0 * 4096 + (tid * 2) * 8);
        bf16x8 pre1 = *(const bf16x8*)(wg + (size_t)s0 * 4096 + (tid * 2 + 1) * 8);

        f32x16 acc[2][2];
        #pragma unroll
        for (int mt = 0; mt < 2; ++mt)
            #pragma unroll
            for (int nt = 0; nt < 2; ++nt)
                acc[mt][nt] = (f32x16)(0.f);

        const u16* xbase = xs + batch * (192 * 64);

        #pragma unroll 2
        for (int ds = 0; ds < 64; ++ds) {
            const int bufo = (ds & 1) * 4096;
            *(bf16x8*)(wsm + bufo + (fo0 * 8 + (fc0 ^ (fo0 & 7))) * 8) = pre0;
            *(bf16x8*)(wsm + bufo + (fo1 * 8 + (fc1 ^ (fo1 & 7))) * 8) = pre1;
            __syncthreads();
            if (ds < 63) {                               // prefetch next s
                const u16* wp = wg + (size_t)(s0 + ds + 1) * 4096;
                pre0 = *(const bf16x8*)(wp + (tid * 2) * 8);
                pre1 = *(const bf16x8*)(wp + (tid * 2 + 1) * 8);
            }
            // A frags: row m = tb_loc + mt*32 + m31, k = g2*8+j (chunk ks*2+g2)
            const int rb = tb_loc + m31 + 63 - ds;
            bf16x8 af[2][4], bfr[2][4];
            #pragma unroll
            for (int mt = 0; mt < 2; ++mt) {
                int r = rb + mt * 32;
                #pragma unroll
                for (int ks = 0; ks < 4; ++ks) {
                    int c = (ks * 2 + g2) ^ (r & 7);
                    af[mt][ks] = *(const bf16x8*)(xbase + (r * 8 + c) * 8);
                }
            }
            // B frags: row o = nt*32 + m31, k = g2*8+j
            #pragma unroll
            for (int nt = 0; nt < 2; ++nt) {
                int o = nt * 32 + m31;
                #pragma unroll
                for (int ks = 0; ks < 4; ++ks) {
                    int c = (ks * 2 + g2) ^ (o & 7);
                    bfr[nt][ks] = *(const bf16x8*)(wsm + bufo + (o * 8 + c) * 8);
                }
            }
            #pragma unroll
            for (int ks = 0; ks < 4; ++ks)
                #pragma unroll
                for (int mt = 0; mt < 2; ++mt)
                    #pragma unroll
                    for (int nt = 0; nt < 2; ++nt)
                        acc[mt][nt] = __builtin_amdgcn_mfma_f32_32x32x16_bf16(
                            af[mt][ks], bfr[nt][ks], acc[mt][nt], 0, 0, 0);
        }

        // ---- epilogue: fp32 atomic accumulation ----
        // C/D: col = lane&31, row = (reg&3) + 8*(reg>>2) + 4*(lane>>5)
        #pragma unroll
        for (int mt = 0; mt < 2; ++mt) {
            #pragma unroll
            for (int nt = 0; nt < 2; ++nt) {
                int o = nt * 32 + m31;
                #pragma unroll
                for (int i = 0; i < 16; ++i) {
                    int row = (i & 3) + 8 * (i >> 2) + 4 * g2;
                    int t = t0 + tb_loc + mt * 32 + row;
                    atomicAdd(out + ((batch << 12) + t) * 64 + o, acc[mt][nt][i]);
                }
            }
        }
    }
}

// ---------------------------------------------------------------------------
extern "C" void kernel_launch(void* const* d_in, const int* in_sizes, int n_in,
                              void* d_out, int out_size, void* d_ws, size_t ws_size,
                              hipStream_t stream) {
    const float* x   = (const float*)d_in[0];   // (2, 4096, 64)
    const float* phi = (const float*)d_in[1];   // (4096, 40)
    const float* M   = (const float*)d_in[2];   // (64, 64, 3)
    const float* Mp  = (const float*)d_in[3];   // (40, 64, 64)
    const float* Mm  = (const float*)d_in[4];   // (40, 64, 64)
    float* out = (float*)d_out;                 // (2, 4096, 64)

    // ws: [0,4) counter | 4096: xpad 2 MiB | wg 32 MiB | ApT/AmT 2x640 KiB
    int* counter = (int*)d_ws;
    u16* xpad = (u16*)((char*)d_ws + 4096);
    u16* wg   = (u16*)((char*)d_ws + 4096 + 2097152);
    float* ApT = (float*)((char*)d_ws + 4096 + 2097152 + 33554432);
    float* AmT = ApT + 40 * 4096;

    hipMemsetAsync(d_ws, 0, 4, stream);
    hipMemsetAsync(d_out, 0, 2 * 4096 * 64 * sizeof(float), stream);
    k_prep<<<1064, 256, 0, stream>>>(x, xpad, Mp, Mm, ApT, AmT);
    k_build_w<<<dim3(64, 16), 256, 0, stream>>>(phi, ApT, AmT, M, wg);
    k_spectral<<<512, 256, 0, stream>>>(xpad, wg, out, counter);
}